// Round 8
// baseline (75.771 us; speedup 1.0000x reference)
//
#include <hip/hip_runtime.h>
#include <hip/hip_bf16.h>

#define EPSF 1e-7f
#define B_ 8
#define H_ 64
#define W_ 64
#define C_ 32
#define HO 58
#define WO 58
#define NF 64
#define KDIM 800

#define XBS 40      // xtb channel stride (bf16): 80B -> +20 banks/col, balanced 8/bank

typedef __bf16 v8bf __attribute__((ext_vector_type(8)));
typedef float  v4f  __attribute__((ext_vector_type(4)));
typedef float  v2f  __attribute__((ext_vector_type(2)));

// ---- pack W into MFMA B-fragment order, bf16 (proven) ----
// Wp[((nt*25+kb)*64+lane)*8+j] = W[f=nt*16+(lane&15)][k=kb*32+(lane>>4)*8+j]
__global__ void k_wpack(const float* __restrict__ W, __bf16* __restrict__ Wp) {
    int t = blockIdx.x*256 + threadIdx.x;   // 51200 total
    int j = t & 7; int lane = (t >> 3) & 63; int rest = t >> 9;
    int kb = rest % 25; int nt = rest / 25;
    int f = nt*16 + (lane & 15);
    int k = kb*32 + (lane >> 4)*8 + j;
    Wp[t] = (__bf16)W[f*KDIM + k];
}

// ---- fused: block = 8 rows x 16 cols (128 px), 8 waves = 4 rowpairs x K-half.
// M=32 per wave (2 rows share one W-fragment set) -> W L2 traffic halves.
// All loop fragments are the round-3/7-proven patterns.
__global__ __launch_bounds__(512, 2)
void k_main(const float* __restrict__ x, const v8bf* __restrict__ Wp,
            const float* __restrict__ bias, float* __restrict__ out) {
    __shared__ __bf16 xtb[14][22][XBS];    // 24,640 B
    __shared__ float  Srow[14][22];        //  1,232 B
    __shared__ float4 pars[128];           //  2,048 B
    __shared__ float  redu[2][4][64][20];  // 40,960 B -> 68,880 B total

    int tid = threadIdx.x;
    int wv = tid >> 6, lane = tid & 63;
    int m = lane & 15, q = lane >> 4;
    int rp = wv & 3, kh = wv >> 2;         // rowpair 0..3, K-half 0..1

    // XCD-aware remap over 256 blocks (8 x 32, bijective): b == XCD id
    int L = blockIdx.x + 4*(blockIdx.y + 8*blockIdx.z);    // 0..255
    int newL = (L & 7)*32 + (L >> 3);
    int b   = newL >> 5;
    int rem = newL & 31;                   // 0..31
    int rg  = rem >> 2;                    // 0..7 -> row group of 8
    int cg  = rem & 3;                     // 0..3 -> col group of 16
    int ho0 = (rg < 7) ? rg*8 : 50;        // rg=7 overlaps rows 50-55 (benign dup)
    int wo0 = cg*16;
    int npx = WO - wo0; if (npx > 16) npx = 16;   // 16,16,16,10

    // phase 0: stage 14 rows x 22 cols x 32ch (rows never exceed 63; col clamp)
    if (tid < 308) {
        int r = tid / 22, c = tid - r*22;
        int xc = wo0 + c; if (xc > W_-1) xc = W_-1;
        const float* src = x + (size_t)((b*H_ + ho0 + r)*W_ + xc)*C_;
        float4 vq[8];
#pragma unroll
        for (int qq = 0; qq < 8; qq++) vq[qq] = *(const float4*)(src + qq*4);
        float s = 0.f;
#pragma unroll
        for (int qq = 0; qq < 8; qq++) s += vq[qq].x + vq[qq].y + vq[qq].z + vq[qq].w;
        Srow[r][c] = s;
#pragma unroll
        for (int h8 = 0; h8 < 4; h8++) {
            v8bf o;
            o[0]=(__bf16)vq[h8*2].x;   o[1]=(__bf16)vq[h8*2].y;
            o[2]=(__bf16)vq[h8*2].z;   o[3]=(__bf16)vq[h8*2].w;
            o[4]=(__bf16)vq[h8*2+1].x; o[5]=(__bf16)vq[h8*2+1].y;
            o[6]=(__bf16)vq[h8*2+1].z; o[7]=(__bf16)vq[h8*2+1].w;
            *(v8bf*)&xtb[r][c][h8*8] = o;
        }
    }
    __syncthreads();

    // phase 1: per-pixel rotation params, 1 thread per px (128 px/block)
    if (tid < 128) {
        int r0 = tid >> 4, c0 = tid & 15;
        float den = 0.f, crn = 0.f, ccn = 0.f;
#pragma unroll
        for (int i = 0; i < 7; i++)
#pragma unroll
            for (int j = 0; j < 7; j++) {
                float v = Srow[r0 + i][c0 + j];
                den += v; crn += v*(float)i; ccn += v*(float)j;
            }
        float dt = den + EPSF;
        float cr = crn/dt - 3.0f;
        float cx = ccn/dt - 3.0f + EPSF;
        float r2 = cr*cr + cx*cx;
        float inv = r2 > 0.f ? rsqrtf(r2) : 0.f;
        float c_ = r2 > 0.f ? cx*inv : 1.0f;
        float s_ = cr*inv;
        const float scale = 1.0f + EPSF;
        float pc  = c_/scale, ps = s_/scale;
        float pxo = (6.0f - (c_*6.0f - s_*6.0f))*0.5f/scale;
        float pyo = (6.0f - (s_*6.0f + c_*6.0f))*0.5f/scale;
        pars[tid] = make_float4(pc, ps, pxo, pyo);
    }
    __syncthreads();
    // ---- xtb/pars read-only until the reduction barrier ----

    int rA = 2*rp, rB = 2*rp + 1;          // this wave's two block-rows
    float4 ppA = pars[(rA << 4) | m];
    float4 ppB = pars[(rB << 4) | m];

    const v8bf* wp = Wp + lane;            // + (nt*25+kb)*64
    const __bf16* patchA = &xtb[rA][m][q*8];
    const __bf16* patchB = &xtb[rB][m][q*8];

    v4f aA0 = {0.f,0.f,0.f,0.f}, aA1 = {0.f,0.f,0.f,0.f};
    v4f aA2 = {0.f,0.f,0.f,0.f}, aA3 = {0.f,0.f,0.f,0.f};
    v4f aB0 = {0.f,0.f,0.f,0.f}, aB1 = {0.f,0.f,0.f,0.f};
    v4f aB2 = {0.f,0.f,0.f,0.f}, aB3 = {0.f,0.f,0.f,0.f};

    int kb0 = kh*13;                       // kh=0: kb 0..12; kh=1: kb 13..24
    int nkb = 13 - kh;
    int kblast = kb0 + nkb - 1;

    auto loadw = [&](v8bf* dst, int kbi) {
        dst[0] = wp[(0*25 + kbi)*64];
        dst[1] = wp[(1*25 + kbi)*64];
        dst[2] = wp[(2*25 + kbi)*64];
        dst[3] = wp[(3*25 + kbi)*64];
    };

    // one M=16 half-step: proven round-3 body (self-contained)
    auto bodyhalf = [&](int kb, const v8bf* wf, const __bf16* patch,
                        float pc, float ps, float pxo, float pyo,
                        v4f& A0, v4f& A1, v4f& A2, v4f& A3) {
        unsigned ukb = (unsigned)kb;
        int py = (int)(ukb/5u);
        int pxx = kb - py*5;
        float yy = (float)(py + 1);
        float xx = (float)(pxx + 1);

        float xin = pc*xx - ps*yy + pxo;
        float yin = ps*xx + pc*yy + pyo;
        float x0f = floorf(xin), y0f = floorf(yin);
        float wx1 = xin - x0f, wx0 = 1.0f - wx1;
        float wy1 = yin - y0f, wy0 = 1.0f - wy1;
        int ix0 = (int)x0f, iy0 = (int)y0f;
        int ix1 = ix0 + 1,  iy1 = iy0 + 1;

        v2f a8[4];
#pragma unroll
        for (int d = 0; d < 4; d++) a8[d] = (v2f){0.f, 0.f};

        auto corner = [&](int yi, int xi, float wgt) {
            bool valid = (xi >= 0) & (xi < 7) & (yi >= 0) & (yi < 7);
            int cy  = yi < 0 ? 0 : (yi > 6 ? 6 : yi);
            int cx2 = xi < 0 ? 0 : (xi > 6 ? 6 : xi);
            float wq = valid ? wgt : 0.0f;
            union { v8bf v; unsigned u[4]; } uv;
            uv.v = *(const v8bf*)(patch + (cy*22 + cx2)*XBS);
            v2f w2 = (v2f){wq, wq};
#pragma unroll
            for (int d = 0; d < 4; d++) {
                v2f val = (v2f){ __uint_as_float(uv.u[d] << 16),
                                 __uint_as_float(uv.u[d] & 0xffff0000u) };
                a8[d] += w2 * val;   // v_pk_fma_f32
            }
        };
        corner(iy0, ix0, wy0*wx0);
        corner(iy0, ix1, wy0*wx1);
        corner(iy1, ix0, wy1*wx0);
        corner(iy1, ix1, wy1*wx1);

        v8bf af;   // A-fragment: row=m(px col), k=kb*32+q*8..+8
#pragma unroll
        for (int d = 0; d < 4; d++) {
            af[2*d]   = (__bf16)a8[d].x;
            af[2*d+1] = (__bf16)a8[d].y;
        }
        A0 = __builtin_amdgcn_mfma_f32_16x16x32_bf16(af, wf[0], A0, 0, 0, 0);
        A1 = __builtin_amdgcn_mfma_f32_16x16x32_bf16(af, wf[1], A1, 0, 0, 0);
        A2 = __builtin_amdgcn_mfma_f32_16x16x32_bf16(af, wf[2], A2, 0, 0, 0);
        A3 = __builtin_amdgcn_mfma_f32_16x16x32_bf16(af, wf[3], A3, 0, 0, 0);
    };

    auto body = [&](int kb, const v8bf* wf) {
        bodyhalf(kb, wf, patchA, ppA.x, ppA.y, ppA.z, ppA.w, aA0, aA1, aA2, aA3);
        bodyhalf(kb, wf, patchB, ppB.x, ppB.y, ppB.z, ppB.w, aB0, aB1, aB2, aB3);
    };

    // round-3-proven ping-pong: W loads for step k+1 in flight during step k
    v8bf wfA[4], wfB[4];
    loadw(wfA, kb0);
    int i = 0;
#pragma unroll 1
    for (; i + 2 <= nkb; i += 2) {
        loadw(wfB, kb0 + i + 1);
        body(kb0 + i, wfA);
        int nx = kb0 + i + 2; if (nx > kblast) nx = kblast;
        loadw(wfA, nx);
        body(kb0 + i + 1, wfB);
    }
    if (i < nkb) body(kblast, wfA);        // tail (kh=0 only: 13th step)

    // split-K reduction: kh=1 waves publish, kh=0 waves sum + store
    if (kh == 1) {
        *(v4f*)&redu[0][rp][lane][0]  = aA0;
        *(v4f*)&redu[0][rp][lane][4]  = aA1;
        *(v4f*)&redu[0][rp][lane][8]  = aA2;
        *(v4f*)&redu[0][rp][lane][12] = aA3;
        *(v4f*)&redu[1][rp][lane][0]  = aB0;
        *(v4f*)&redu[1][rp][lane][4]  = aB1;
        *(v4f*)&redu[1][rp][lane][8]  = aB2;
        *(v4f*)&redu[1][rp][lane][12] = aB3;
    }
    __syncthreads();
    if (kh == 0) {
        aA0 += *(const v4f*)&redu[0][rp][lane][0];
        aA1 += *(const v4f*)&redu[0][rp][lane][4];
        aA2 += *(const v4f*)&redu[0][rp][lane][8];
        aA3 += *(const v4f*)&redu[0][rp][lane][12];
        aB0 += *(const v4f*)&redu[1][rp][lane][0];
        aB1 += *(const v4f*)&redu[1][rp][lane][4];
        aB2 += *(const v4f*)&redu[1][rp][lane][8];
        aB3 += *(const v4f*)&redu[1][rp][lane][12];

        float bv0 = bias[m], bv1 = bias[16 + m];
        float bv2 = bias[32 + m], bv3 = bias[48 + m];

        int hoA = ho0 + rA;                // always < 58 by construction
        int hoB = ho0 + rB;
        size_t rbA = (size_t)(b*HO + hoA)*WO + wo0;
        size_t rbB = (size_t)(b*HO + hoB)*WO + wo0;
#pragma unroll
        for (int r = 0; r < 4; r++) {
            int px = q*4 + r;              // D row = (lane>>4)*4 + reg -> pixel col
            if (px < npx) {
                float* opA = out + (rbA + px)*NF + m;
                opA[0]  = aA0[r] + bv0;
                opA[16] = aA1[r] + bv1;
                opA[32] = aA2[r] + bv2;
                opA[48] = aA3[r] + bv3;
                float* opB = out + (rbB + px)*NF + m;
                opB[0]  = aB0[r] + bv0;
                opB[16] = aB1[r] + bv1;
                opB[32] = aB2[r] + bv2;
                opB[48] = aB3[r] + bv3;
            }
        }
    }
}

extern "C" void kernel_launch(void* const* d_in, const int* in_sizes, int n_in,
                              void* d_out, int out_size, void* d_ws, size_t ws_size,
                              hipStream_t stream) {
    const float* x    = (const float*)d_in[0];
    const float* W    = (const float*)d_in[1];
    const float* bias = (const float*)d_in[2];
    float* out = (float*)d_out;
    __bf16* Wp = (__bf16*)d_ws;                    // 102,400 B

    k_wpack<<<dim3(200), 256, 0, stream>>>(W, Wp);
    k_main<<<dim3(4, 8, B_), 512, 0, stream>>>(x, (const v8bf*)Wp, bias, out);
}